// Round 4
// baseline (637.149 us; speedup 1.0000x reference)
//
#include <hip/hip_runtime.h>

#define N_NODES 100000
#define N_TYPES 7
#define N_EDGES 400000
#define DIM 128
#define NTOT (N_TYPES * N_NODES)   // 700000
#define ETOT (N_TYPES * N_EDGES)   // 2800000

typedef short v8s __attribute__((ext_vector_type(8)));   // 8 bf16 (4 VGPRs)
typedef float v4f __attribute__((ext_vector_type(4)));   // 4 f32 acc

__device__ __forceinline__ float bf2f(unsigned short u) {
    return __uint_as_float(((unsigned int)u) << 16);
}
__device__ __forceinline__ unsigned short f2bf(float f) {
    unsigned int x = __float_as_uint(f);
    return (unsigned short)((x + 0x7FFFu + ((x >> 16) & 1u)) >> 16);   // RNE
}

// ---------------------------------------------------------------------------
// casts
// ---------------------------------------------------------------------------
__global__ __launch_bounds__(256) void cast_x_kernel(
    const float* __restrict__ x, unsigned short* __restrict__ xb)
{
    int i = blockIdx.x * 256 + threadIdx.x;            // one float4 each
    if (i >= N_NODES * DIM / 4) return;
    float4 v = reinterpret_cast<const float4*>(x)[i];
    ushort4 o;
    o.x = f2bf(v.x); o.y = f2bf(v.y); o.z = f2bf(v.z); o.w = f2bf(v.w);
    reinterpret_cast<ushort4*>(xb)[i] = o;
}

// WT[t][j][k] = bf16(W[t][k][j])
__global__ __launch_bounds__(256) void cast_wt_kernel(
    const float* __restrict__ W, unsigned short* __restrict__ WT)
{
    int i = blockIdx.x * 256 + threadIdx.x;
    if (i >= N_TYPES * DIM * DIM) return;
    int t = i >> 14, r = i & 16383, j = r >> 7, k = r & 127;
    WT[i] = f2bf(W[(t << 14) + (k << 7) + j]);
}

__global__ __launch_bounds__(128) void bsum_kernel(
    const float* __restrict__ b, float* __restrict__ bsum)
{
    int j = threadIdx.x;
    float s = 0.f;
    for (int t = 0; t < N_TYPES; ++t) s += b[t * DIM + j];
    bsum[j] = s;
}

// ---------------------------------------------------------------------------
// CSR build. type = blockIdx&7 so each XCD's L2 owns one type's slices.
// ---------------------------------------------------------------------------
#define BPT 256
__global__ __launch_bounds__(256) void hist_kernel(
    const int* __restrict__ ei, int* __restrict__ deg)
{
    int m = blockIdx.x & 7;
    if (m >= N_TYPES) return;
    int bi = blockIdx.x >> 3;
    const int* dstp = ei + (size_t)m * 2 * N_EDGES + N_EDGES;
    int* degt = deg + m * N_NODES;
    for (int e = bi * 256 + threadIdx.x; e < N_EDGES; e += BPT * 256)
        atomicAdd(&degt[dstp[e]], 1);
}

__global__ __launch_bounds__(256) void scan1_kernel(
    const int* __restrict__ deg, int* __restrict__ offs, int* __restrict__ bsum)
{
    __shared__ int s[256];
    int tid = threadIdx.x;
    int base = blockIdx.x * 1024 + tid * 4;
    int v[4];
    int tot = 0;
#pragma unroll
    for (int j = 0; j < 4; ++j) {
        v[j] = (base + j < NTOT) ? deg[base + j] : 0;
        tot += v[j];
    }
    s[tid] = tot;
    __syncthreads();
    for (int off = 1; off < 256; off <<= 1) {
        int t2 = (tid >= off) ? s[tid - off] : 0;
        __syncthreads();
        s[tid] += t2;
        __syncthreads();
    }
    if (tid == 255) bsum[blockIdx.x] = s[255];
    int run = s[tid] - tot;
#pragma unroll
    for (int j = 0; j < 4; ++j) {
        if (base + j < NTOT) offs[base + j] = run;
        run += v[j];
    }
}

__global__ __launch_bounds__(1024) void scan2_kernel(int* __restrict__ bsum, int nb)
{
    __shared__ int s[1024];
    int tid = threadIdx.x;
    int v = (tid < nb) ? bsum[tid] : 0;
    s[tid] = v;
    __syncthreads();
    for (int off = 1; off < 1024; off <<= 1) {
        int t2 = (tid >= off) ? s[tid - off] : 0;
        __syncthreads();
        s[tid] += t2;
        __syncthreads();
    }
    if (tid < nb) bsum[tid] = s[tid] - v;
}

__global__ __launch_bounds__(256) void scan3_kernel(
    int* __restrict__ offs, int* __restrict__ cursor, const int* __restrict__ bsum)
{
    int i = blockIdx.x * 256 + threadIdx.x;
    if (i < NTOT) {
        int v = offs[i] + bsum[i >> 10];
        offs[i] = v;
        cursor[i] = v;
    }
    if (i == 0) offs[NTOT] = ETOT;
}

__global__ __launch_bounds__(256) void fill_kernel(
    const int* __restrict__ ei, int* __restrict__ cursor, int* __restrict__ srcperm)
{
    int m = blockIdx.x & 7;
    if (m >= N_TYPES) return;
    int bi = blockIdx.x >> 3;
    const int* base = ei + (size_t)m * 2 * N_EDGES;
    int* curt = cursor + m * N_NODES;
    for (int e = bi * 256 + threadIdx.x; e < N_EDGES; e += BPT * 256) {
        int s = base[e];
        int d = base[N_EDGES + e];
        int pos = atomicAdd(&curt[d], 1);
        srcperm[pos] = s;
    }
}

// ---------------------------------------------------------------------------
// Fused aggregate + MFMA GEMM.
// Block: 256 thr = 4 waves, 64 output rows. Per type t:
//   stage WT_t -> sB (swizzled); each wave aggregates its 16 rows' means
//   (scalar CSR walk, 4 gathers in flight) -> sA (swizzled, wave-private);
//   32 MFMA per wave accumulate across all 7 types; single out write.
// ---------------------------------------------------------------------------
__global__ __launch_bounds__(256) void fused_kernel(
    const unsigned short* __restrict__ xb,
    const int* __restrict__ offs,
    const int* __restrict__ srcperm,
    const unsigned short* __restrict__ WT,
    const float* __restrict__ bsum,
    float* __restrict__ out)
{
    __shared__ unsigned short sB[DIM * DIM];   // 32 KB, swizzled
    __shared__ unsigned short sA[64 * DIM];    // 16 KB, swizzled

    const int tid = threadIdx.x;
    const int lane = tid & 63;
    const int wave = tid >> 6;
    const int rlo = lane & 15;
    const int khi = lane >> 4;                 // 0..3
    const int row0 = blockIdx.x * 64;
    const int gbase = __builtin_amdgcn_readfirstlane(row0 + wave * 16);
    const int loff = lane << 2;                // this lane's byte offset in a row

    v4f acc[8];
#pragma unroll
    for (int n = 0; n < 8; ++n) acc[n] = (v4f){0.f, 0.f, 0.f, 0.f};

    for (int t = 0; t < N_TYPES; ++t) {
        __syncthreads();                       // previous MFMA done with sB
        // ---- stage WT_t into sB (8 x uint4 per thread, XOR-swizzled) ----
        const uint4* gw = reinterpret_cast<const uint4*>(WT + ((size_t)t << 14));
#pragma unroll
        for (int i = 0; i < 8; ++i) {
            int c = tid + (i << 8);            // 0..2047
            uint4 v = gw[c];
            int L = c << 4;
            int row = L >> 8;
            int sb = (row << 8) | ((L & 255) ^ ((row & 7) << 4));
            *reinterpret_cast<uint4*>(reinterpret_cast<char*>(sB) + sb) = v;
        }

        // ---- aggregate this wave's 16 rows into sA ----
        const int* offt = offs + t * N_NODES;
        for (int i = 0; i < 16; ++i) {
            int g = gbase + i;
            if (g >= N_NODES) continue;        // wave-uniform; garbage rows discarded
            int beg = __builtin_amdgcn_readfirstlane(offt[g]);
            int end = __builtin_amdgcn_readfirstlane(offt[g + 1]);
            float a0 = 0.f, a1 = 0.f;
            int e = beg;
            for (; e + 4 <= end; e += 4) {     // 4 independent gathers in flight
                int s0 = __builtin_amdgcn_readfirstlane(srcperm[e]);
                int s1 = __builtin_amdgcn_readfirstlane(srcperm[e + 1]);
                int s2 = __builtin_amdgcn_readfirstlane(srcperm[e + 2]);
                int s3 = __builtin_amdgcn_readfirstlane(srcperm[e + 3]);
                unsigned int u0 = *reinterpret_cast<const unsigned int*>(
                    reinterpret_cast<const char*>(xb) + ((size_t)s0 << 8) + loff);
                unsigned int u1 = *reinterpret_cast<const unsigned int*>(
                    reinterpret_cast<const char*>(xb) + ((size_t)s1 << 8) + loff);
                unsigned int u2 = *reinterpret_cast<const unsigned int*>(
                    reinterpret_cast<const char*>(xb) + ((size_t)s2 << 8) + loff);
                unsigned int u3 = *reinterpret_cast<const unsigned int*>(
                    reinterpret_cast<const char*>(xb) + ((size_t)s3 << 8) + loff);
                a0 += __uint_as_float(u0 << 16); a1 += __uint_as_float(u0 & 0xFFFF0000u);
                a0 += __uint_as_float(u1 << 16); a1 += __uint_as_float(u1 & 0xFFFF0000u);
                a0 += __uint_as_float(u2 << 16); a1 += __uint_as_float(u2 & 0xFFFF0000u);
                a0 += __uint_as_float(u3 << 16); a1 += __uint_as_float(u3 & 0xFFFF0000u);
            }
            for (; e < end; ++e) {
                int s0 = __builtin_amdgcn_readfirstlane(srcperm[e]);
                unsigned int u0 = *reinterpret_cast<const unsigned int*>(
                    reinterpret_cast<const char*>(xb) + ((size_t)s0 << 8) + loff);
                a0 += __uint_as_float(u0 << 16); a1 += __uint_as_float(u0 & 0xFFFF0000u);
            }
            float inv = 1.0f / fmaxf((float)(end - beg), 1.0f);
            a0 *= inv; a1 *= inv;
            unsigned int pk;
            asm("v_cvt_pk_bf16_f32 %0, %1, %2" : "=v"(pk) : "v"(a0), "v"(a1));
            int r = (wave << 4) + i;
            int ab = (r << 8) | (loff ^ ((r & 7) << 4));
            *reinterpret_cast<unsigned int*>(reinterpret_cast<char*>(sA) + ab) = pk;
        }
        __syncthreads();                       // sB ready (sA is wave-private)

        // ---- MFMA: 16 rows x 128 cols per wave ----
        const int arow = (wave << 4) + rlo;
#pragma unroll
        for (int k0 = 0; k0 < DIM; k0 += 32) {
            int kb = (k0 + (khi << 3)) << 1;
            int ab = (arow << 8) | (kb ^ ((arow & 7) << 4));
            v8s a = *reinterpret_cast<const v8s*>(reinterpret_cast<char*>(sA) + ab);
#pragma unroll
            for (int n = 0; n < 8; ++n) {
                int jrow = (n << 4) | rlo;
                int sb = (jrow << 8) | (kb ^ ((jrow & 7) << 4));
                v8s bf = *reinterpret_cast<const v8s*>(reinterpret_cast<char*>(sB) + sb);
                acc[n] = __builtin_amdgcn_mfma_f32_16x16x32_bf16(a, bf, acc[n], 0, 0, 0);
            }
        }
    }

    // ---- epilogue: out = (acc + bsum) / 7 ----
    const float inv7 = 1.0f / 7.0f;
#pragma unroll
    for (int n = 0; n < 8; ++n) {
        int col = (n << 4) | rlo;
        float bs = bsum[col];
#pragma unroll
        for (int r = 0; r < 4; ++r) {
            int row = row0 + (wave << 4) + (khi << 2) + r;
            if (row < N_NODES)
                out[((size_t)row << 7) + col] = (acc[n][r] + bs) * inv7;
        }
    }
}

extern "C" void kernel_launch(void* const* d_in, const int* in_sizes, int n_in,
                              void* d_out, int out_size, void* d_ws, size_t ws_size,
                              hipStream_t stream) {
    const float* x  = (const float*)d_in[0];
    const int*   ei = (const int*)d_in[1];     // [N_TYPES, 2, N_EDGES] int32
    const float* W  = (const float*)d_in[2];
    const float* b  = (const float*)d_in[3];
    float* out = (float*)d_out;

    // ---- workspace layout ----
    char* p = (char*)d_ws;
    unsigned short* xb = (unsigned short*)p;          p += (size_t)N_NODES * DIM * 2;       // 25.6 MB
    unsigned short* WT = (unsigned short*)p;          p += (size_t)N_TYPES * DIM * DIM * 2; // 229 KB
    float* bsum = (float*)p;                          p += 512;
    int* srcperm = (int*)p;                           p += (size_t)ETOT * 4;                // 11.2 MB
    int* deg = (int*)p;                               p += (size_t)NTOT * 4;
    int* offs = (int*)p;                              p += (size_t)(NTOT + 1) * 4;
    int* cursor = (int*)p;                            p += (size_t)NTOT * 4;
    int* bscan = (int*)p;                             p += 1024 * 4;

    const int NB = (NTOT + 1023) / 1024;              // 684

    cast_x_kernel<<<(N_NODES * DIM / 4 + 255) / 256, 256, 0, stream>>>(x, xb);
    cast_wt_kernel<<<(N_TYPES * DIM * DIM + 255) / 256, 256, 0, stream>>>(W, WT);
    bsum_kernel<<<1, 128, 0, stream>>>(b, bsum);

    hipMemsetAsync(deg, 0, (size_t)NTOT * sizeof(int), stream);
    hist_kernel<<<BPT * 8, 256, 0, stream>>>(ei, deg);
    scan1_kernel<<<NB, 256, 0, stream>>>(deg, offs, bscan);
    scan2_kernel<<<1, 1024, 0, stream>>>(bscan, NB);
    scan3_kernel<<<(NTOT + 255) / 256, 256, 0, stream>>>(offs, cursor, bscan);
    fill_kernel<<<BPT * 8, 256, 0, stream>>>(ei, cursor, srcperm);

    const int fused_blocks = (N_NODES + 63) / 64;     // 1563
    fused_kernel<<<fused_blocks, 256, 0, stream>>>(xb, offs, srcperm, WT, bsum, out);
}

// Round 5
// 446.395 us; speedup vs baseline: 1.4273x; 1.4273x over previous
//
#include <hip/hip_runtime.h>

#define N_NODES 100000
#define N_TYPES 7
#define N_EDGES 400000
#define DIM 128
#define NTOT (N_TYPES * N_NODES)   // 700000
#define ETOT (N_TYPES * N_EDGES)   // 2800000

typedef short v8s __attribute__((ext_vector_type(8)));   // 8 bf16 (4 VGPRs)
typedef float v4f __attribute__((ext_vector_type(4)));   // 4 f32 acc

__device__ __forceinline__ float bf2f(unsigned short u) {
    return __uint_as_float(((unsigned int)u) << 16);
}
__device__ __forceinline__ unsigned short f2bf(float f) {
    unsigned int x = __float_as_uint(f);
    return (unsigned short)((x + 0x7FFFu + ((x >> 16) & 1u)) >> 16);   // RNE
}

// ---------------------------------------------------------------------------
// casts
// ---------------------------------------------------------------------------
__global__ __launch_bounds__(256) void cast_x_kernel(
    const float* __restrict__ x, unsigned short* __restrict__ xb)
{
    int i = blockIdx.x * 256 + threadIdx.x;            // one float4 each
    if (i >= N_NODES * DIM / 4) return;
    float4 v = reinterpret_cast<const float4*>(x)[i];
    ushort4 o;
    o.x = f2bf(v.x); o.y = f2bf(v.y); o.z = f2bf(v.z); o.w = f2bf(v.w);
    reinterpret_cast<ushort4*>(xb)[i] = o;
}

// WT[t][j][k] = bf16(W[t][k][j])
__global__ __launch_bounds__(256) void cast_wt_kernel(
    const float* __restrict__ W, unsigned short* __restrict__ WT)
{
    int i = blockIdx.x * 256 + threadIdx.x;
    if (i >= N_TYPES * DIM * DIM) return;
    int t = i >> 14, r = i & 16383, j = r >> 7, k = r & 127;
    WT[i] = f2bf(W[(t << 14) + (k << 7) + j]);
}

__global__ __launch_bounds__(128) void bsum_kernel(
    const float* __restrict__ b, float* __restrict__ bsum)
{
    int j = threadIdx.x;
    float s = 0.f;
    for (int t = 0; t < N_TYPES; ++t) s += b[t * DIM + j];
    bsum[j] = s;
}

// ---------------------------------------------------------------------------
// CSR build. type = blockIdx&7 so each XCD's L2 owns one type's slices.
// ---------------------------------------------------------------------------
#define BPT 256
__global__ __launch_bounds__(256) void hist_kernel(
    const int* __restrict__ ei, int* __restrict__ deg)
{
    int m = blockIdx.x & 7;
    if (m >= N_TYPES) return;
    int bi = blockIdx.x >> 3;
    const int* dstp = ei + (size_t)m * 2 * N_EDGES + N_EDGES;
    int* degt = deg + m * N_NODES;
    for (int e = bi * 256 + threadIdx.x; e < N_EDGES; e += BPT * 256)
        atomicAdd(&degt[dstp[e]], 1);
}

__global__ __launch_bounds__(256) void scan1_kernel(
    const int* __restrict__ deg, int* __restrict__ offs, int* __restrict__ bsum)
{
    __shared__ int s[256];
    int tid = threadIdx.x;
    int base = blockIdx.x * 1024 + tid * 4;
    int v[4];
    int tot = 0;
#pragma unroll
    for (int j = 0; j < 4; ++j) {
        v[j] = (base + j < NTOT) ? deg[base + j] : 0;
        tot += v[j];
    }
    s[tid] = tot;
    __syncthreads();
    for (int off = 1; off < 256; off <<= 1) {
        int t2 = (tid >= off) ? s[tid - off] : 0;
        __syncthreads();
        s[tid] += t2;
        __syncthreads();
    }
    if (tid == 255) bsum[blockIdx.x] = s[255];
    int run = s[tid] - tot;
#pragma unroll
    for (int j = 0; j < 4; ++j) {
        if (base + j < NTOT) offs[base + j] = run;
        run += v[j];
    }
}

__global__ __launch_bounds__(1024) void scan2_kernel(int* __restrict__ bsum, int nb)
{
    __shared__ int s[1024];
    int tid = threadIdx.x;
    int v = (tid < nb) ? bsum[tid] : 0;
    s[tid] = v;
    __syncthreads();
    for (int off = 1; off < 1024; off <<= 1) {
        int t2 = (tid >= off) ? s[tid - off] : 0;
        __syncthreads();
        s[tid] += t2;
        __syncthreads();
    }
    if (tid < nb) bsum[tid] = s[tid] - v;
}

__global__ __launch_bounds__(256) void scan3_kernel(
    int* __restrict__ offs, int* __restrict__ cursor, const int* __restrict__ bsum)
{
    int i = blockIdx.x * 256 + threadIdx.x;
    if (i < NTOT) {
        int v = offs[i] + bsum[i >> 10];
        offs[i] = v;
        cursor[i] = v;
    }
    if (i == 0) offs[NTOT] = ETOT;
}

__global__ __launch_bounds__(256) void fill_kernel(
    const int* __restrict__ ei, int* __restrict__ cursor, int* __restrict__ srcperm)
{
    int m = blockIdx.x & 7;
    if (m >= N_TYPES) return;
    int bi = blockIdx.x >> 3;
    const int* base = ei + (size_t)m * 2 * N_EDGES;
    int* curt = cursor + m * N_NODES;
    for (int e = bi * 256 + threadIdx.x; e < N_EDGES; e += BPT * 256) {
        int s = base[e];
        int d = base[N_EDGES + e];
        int pos = atomicAdd(&curt[d], 1);
        srcperm[pos] = s;
    }
}

// ---------------------------------------------------------------------------
// Aggregate: 16 lanes per (type,node) group -> 4 independent CSR chains per
// wave, predicated to the wave-max degree so every iteration issues 4
// independent 16B gathers. bf16 gather, f32 accum (w*fmac), bf16 mean out.
// ---------------------------------------------------------------------------
__global__ __launch_bounds__(256) void aggregate_kernel(
    const unsigned short* __restrict__ xb,
    const int* __restrict__ offs,       // [NTOT+1], contiguous over (t,g)
    const int* __restrict__ srcperm,
    unsigned short* __restrict__ meanout,
    int grp0, int ngrp)
{
    int gi = blockIdx.x * 16 + (threadIdx.x >> 4);     // group within range
    if (gi >= ngrp) return;
    int grp = grp0 + gi;
    int l = threadIdx.x & 15;                          // lane in group

    int beg = offs[grp];
    int end = offs[grp + 1];
    int m = end - beg;

    // wave-max of m across the 4 groups (m is uniform within each 16-lane group)
    int mm = m;
    mm = max(mm, __shfl_xor(mm, 16));
    mm = max(mm, __shfl_xor(mm, 32));

    float a[8];
#pragma unroll
    for (int j = 0; j < 8; ++j) a[j] = 0.f;

    const int eSafe = min(beg, ETOT - 1);
#pragma unroll 2
    for (int i = 0; i < mm; ++i) {
        bool valid = i < m;
        int e = valid ? (beg + i) : eSafe;
        int s = srcperm[e];
        uint4 v = *reinterpret_cast<const uint4*>(
            reinterpret_cast<const char*>(xb) + ((size_t)s << 8) + (l << 4));
        float w = valid ? 1.f : 0.f;
        a[0] += w * __uint_as_float(v.x << 16);
        a[1] += w * __uint_as_float(v.x & 0xFFFF0000u);
        a[2] += w * __uint_as_float(v.y << 16);
        a[3] += w * __uint_as_float(v.y & 0xFFFF0000u);
        a[4] += w * __uint_as_float(v.z << 16);
        a[5] += w * __uint_as_float(v.z & 0xFFFF0000u);
        a[6] += w * __uint_as_float(v.w << 16);
        a[7] += w * __uint_as_float(v.w & 0xFFFF0000u);
    }

    float inv = 1.0f / fmaxf((float)m, 1.0f);
    unsigned int p0, p1, p2, p3;
    asm("v_cvt_pk_bf16_f32 %0, %1, %2" : "=v"(p0) : "v"(a[0] * inv), "v"(a[1] * inv));
    asm("v_cvt_pk_bf16_f32 %0, %1, %2" : "=v"(p1) : "v"(a[2] * inv), "v"(a[3] * inv));
    asm("v_cvt_pk_bf16_f32 %0, %1, %2" : "=v"(p2) : "v"(a[4] * inv), "v"(a[5] * inv));
    asm("v_cvt_pk_bf16_f32 %0, %1, %2" : "=v"(p3) : "v"(a[6] * inv), "v"(a[7] * inv));
    uint4 o = make_uint4(p0, p1, p2, p3);
    *reinterpret_cast<uint4*>(
        reinterpret_cast<char*>(meanout) + ((size_t)gi << 8) + (l << 4)) = o;
}

// ---------------------------------------------------------------------------
// MFMA GEMM: out[100k][128] (f32) = sum_t mean_t[100k][128] @ W_t + bsum, /7.
// ---------------------------------------------------------------------------
__global__ __launch_bounds__(256) void matmul_kernel(
    const unsigned short* __restrict__ meanall, size_t meanStride,
    int t0, int nt,
    const unsigned short* __restrict__ WT,
    const float* __restrict__ bsum,
    float* __restrict__ out, int accum)
{
    __shared__ unsigned short sB[DIM * DIM];   // 32 KB, swizzled

    const int tid = threadIdx.x;
    const int wave = tid >> 6;
    const int lane = tid & 63;
    const int rlo = lane & 15;
    const int khi = lane >> 4;                 // 0..3
    const int row0 = blockIdx.x * 64 + wave * 16;

    v4f acc[8];
#pragma unroll
    for (int n = 0; n < 8; ++n) acc[n] = (v4f){0.f, 0.f, 0.f, 0.f};

    for (int tt = 0; tt < nt; ++tt) {
        int t = t0 + tt;
        __syncthreads();
        const uint4* gw = reinterpret_cast<const uint4*>(WT + ((size_t)t << 14));
#pragma unroll
        for (int i = 0; i < 8; ++i) {
            int c = tid + (i << 8);            // 0..2047
            uint4 v = gw[c];
            int L = c << 4;
            int row = L >> 8;
            int sb = (row << 8) | ((L & 255) ^ ((row & 7) << 4));
            *reinterpret_cast<uint4*>(reinterpret_cast<char*>(sB) + sb) = v;
        }
        __syncthreads();

        int rowA = row0 + rlo;
        if (rowA >= N_NODES) rowA = N_NODES - 1;
        const unsigned short* arow = meanall + (size_t)tt * meanStride + ((size_t)rowA << 7);

#pragma unroll
        for (int k0 = 0; k0 < DIM; k0 += 32) {
            v8s a = *reinterpret_cast<const v8s*>(arow + k0 + (khi << 3));
#pragma unroll
            for (int n = 0; n < 8; ++n) {
                int jrow = (n << 4) | rlo;
                int kb = (k0 + (khi << 3)) << 1;
                int sb = (jrow << 8) | (kb ^ ((jrow & 7) << 4));
                v8s bf = *reinterpret_cast<const v8s*>(reinterpret_cast<char*>(sB) + sb);
                acc[n] = __builtin_amdgcn_mfma_f32_16x16x32_bf16(a, bf, acc[n], 0, 0, 0);
            }
        }
    }

    const float inv7 = 1.0f / 7.0f;
#pragma unroll
    for (int n = 0; n < 8; ++n) {
        int col = (n << 4) | rlo;
        float bs = bsum[col];
#pragma unroll
        for (int r = 0; r < 4; ++r) {
            int row = row0 + (khi << 2) + r;
            if (row < N_NODES) {
                float* p = out + ((size_t)row << 7) + col;
                if (accum) *p += acc[n][r] * inv7;
                else       *p = (acc[n][r] + bs) * inv7;
            }
        }
    }
}

__global__ __launch_bounds__(256) void out_init_kernel(
    const float* __restrict__ bsum, float* __restrict__ out)
{
    int i = blockIdx.x * 256 + threadIdx.x;    // one float4 each
    if (i >= N_NODES * DIM / 4) return;
    int c4 = (i & 31) * 4;
    const float inv7 = 1.0f / 7.0f;
    float4 bv = *reinterpret_cast<const float4*>(bsum + c4);
    float4 o = make_float4(bv.x * inv7, bv.y * inv7, bv.z * inv7, bv.w * inv7);
    reinterpret_cast<float4*>(out)[i] = o;
}

extern "C" void kernel_launch(void* const* d_in, const int* in_sizes, int n_in,
                              void* d_out, int out_size, void* d_ws, size_t ws_size,
                              hipStream_t stream) {
    const float* x  = (const float*)d_in[0];
    const int*   ei = (const int*)d_in[1];     // [N_TYPES, 2, N_EDGES] int32
    const float* W  = (const float*)d_in[2];
    const float* b  = (const float*)d_in[3];
    float* out = (float*)d_out;

    // ---- workspace layout ----
    char* p = (char*)d_ws;
    unsigned short* xb = (unsigned short*)p;          p += (size_t)N_NODES * DIM * 2;       // 25.6 MB
    unsigned short* WT = (unsigned short*)p;          p += (size_t)N_TYPES * DIM * DIM * 2; // 229 KB
    float* bsum = (float*)p;                          p += 512;
    int* srcperm = (int*)p;                           p += (size_t)ETOT * 4;                // 11.2 MB
    int* deg = (int*)p;                               p += (size_t)NTOT * 4;
    int* offs = (int*)p;                              p += (size_t)(NTOT + 1) * 4;
    int* cursor = (int*)p;                            p += (size_t)NTOT * 4;
    int* bscan = (int*)p;                             p += 1024 * 4;
    p = (char*)(((uintptr_t)p + 15) & ~(uintptr_t)15);
    unsigned short* meanbuf = (unsigned short*)p;
    size_t mean1_bytes = (size_t)N_NODES * DIM * 2;   // 25.6 MB per type
    size_t used = (size_t)(p - (char*)d_ws);
    bool fused = (ws_size >= used + 7 * mean1_bytes);

    const int NB = (NTOT + 1023) / 1024;              // 684

    cast_x_kernel<<<(N_NODES * DIM / 4 + 255) / 256, 256, 0, stream>>>(x, xb);
    cast_wt_kernel<<<(N_TYPES * DIM * DIM + 255) / 256, 256, 0, stream>>>(W, WT);
    bsum_kernel<<<1, 128, 0, stream>>>(b, bsum);

    hipMemsetAsync(deg, 0, (size_t)NTOT * sizeof(int), stream);
    hist_kernel<<<BPT * 8, 256, 0, stream>>>(ei, deg);
    scan1_kernel<<<NB, 256, 0, stream>>>(deg, offs, bscan);
    scan2_kernel<<<1, 1024, 0, stream>>>(bscan, NB);
    scan3_kernel<<<(NTOT + 255) / 256, 256, 0, stream>>>(offs, cursor, bscan);
    fill_kernel<<<BPT * 8, 256, 0, stream>>>(ei, cursor, srcperm);

    const int matmul_blocks = (N_NODES + 63) / 64;    // 1563

    if (fused) {
        size_t meanStride = (size_t)N_NODES * DIM;    // ushorts
        aggregate_kernel<<<(NTOT + 15) / 16, 256, 0, stream>>>(
            xb, offs, srcperm, meanbuf, 0, NTOT);
        matmul_kernel<<<matmul_blocks, 256, 0, stream>>>(
            meanbuf, meanStride, 0, N_TYPES, WT, bsum, out, 0);
    } else {
        out_init_kernel<<<(N_NODES * DIM / 4 + 255) / 256, 256, 0, stream>>>(bsum, out);
        for (int t = 0; t < N_TYPES; ++t) {
            aggregate_kernel<<<(N_NODES + 15) / 16, 256, 0, stream>>>(
                xb, offs, srcperm, meanbuf, t * N_NODES, N_NODES);
            matmul_kernel<<<matmul_blocks, 256, 0, stream>>>(
                meanbuf, 0, t, 1, WT, bsum, out, 1);
        }
    }
}